// Round 1
// baseline (576.294 us; speedup 1.0000x reference)
//
#include <hip/hip_runtime.h>

#define T_DIM 4096
#define B_DIM 4
#define NF 131
#define INV_SQRT_D 0.08838834764831845f
#define JITTER_F 1e-6f
#define LSTRIDE 136  // 128 + 8 bf16 pad: row stride 272 B, keeps 16B alignment, uniform LDS banks

typedef __bf16 bf16_t;
typedef bf16_t bf16x8 __attribute__((ext_vector_type(8)));
typedef bf16_t bf16x2 __attribute__((ext_vector_type(2)));
typedef float f32x4 __attribute__((ext_vector_type(4)));

// Kernel 1: per-row precompute.
// One wave per (b,t) row: mean copy, z -> bf16 (scaled by 1/sqrt(128)),
// h = 0.5*sum(z^2) (fp32), v, softplus(noise).
__global__ __launch_bounds__(256) void prep_kernel(
    const float* __restrict__ in, float* __restrict__ mean_out,
    bf16_t* __restrict__ Zb, float* __restrict__ h,
    float* __restrict__ v, float* __restrict__ noise) {
  const int row = blockIdx.x * 4 + (threadIdx.x >> 6);
  const int lane = threadIdx.x & 63;
  const float* x = in + (long)row * NF;
  float z0 = x[1 + lane * 2] * INV_SQRT_D;
  float z1 = x[2 + lane * 2] * INV_SQRT_D;
  bf16x2 p;
  p.x = (bf16_t)z0;
  p.y = (bf16_t)z1;
  *(bf16x2*)(Zb + (long)row * 128 + lane * 2) = p;
  float s = z0 * z0 + z1 * z1;
  #pragma unroll
  for (int m = 32; m > 0; m >>= 1) s += __shfl_down(s, m);
  if (lane == 0) {
    h[row] = 0.5f * s;
    mean_out[row] = x[0];
    v[row] = x[129];
    float t = x[130];
    // softplus: log1p(exp(t)); for large t, exp overflows -> use t directly
    noise[row] = (t > 15.0f) ? t : log1pf(__expf(t));
  }
}

// Kernel 2: 128x128 output tile per block.
// gram via mfma_f32_16x16x32_bf16; epilogue: exp(gram - h_i - h_j)*v_i*v_j,
// dual nontemporal store to f_cov and y_cov with diagonal fixups.
__global__ __launch_bounds__(256) void cov_kernel(
    const bf16_t* __restrict__ Zb, const float* __restrict__ h,
    const float* __restrict__ v, const float* __restrict__ noise,
    float* __restrict__ f_cov, float* __restrict__ y_cov) {
  __shared__ __align__(16) bf16_t As[128 * LSTRIDE];
  __shared__ __align__(16) bf16_t Bs[128 * LSTRIDE];
  __shared__ float hA[128], vA[128], nA[128], hB[128], vB[128];

  const int jt = blockIdx.x, it = blockIdx.y, b = blockIdx.z;
  const int i0 = it * 128, j0 = jt * 128;
  const int tid = threadIdx.x;

  const bf16_t* gA = Zb + ((long)b * T_DIM + i0) * 128;
  const bf16_t* gB = Zb + ((long)b * T_DIM + j0) * 128;
  // Stage 32 KB per operand: 2048 chunks of 16 B; rows are contiguous in Zb.
  #pragma unroll
  for (int c = tid; c < 2048; c += 256) {
    const int r = c >> 4, c8 = c & 15;
    *(float4*)(As + r * LSTRIDE + c8 * 8) = ((const float4*)gA)[c];
    *(float4*)(Bs + r * LSTRIDE + c8 * 8) = ((const float4*)gB)[c];
  }
  if (tid < 128) {
    hA[tid] = h[b * T_DIM + i0 + tid];
    vA[tid] = v[b * T_DIM + i0 + tid];
    nA[tid] = noise[b * T_DIM + i0 + tid];
  } else {
    const int t2 = tid - 128;
    hB[t2] = h[b * T_DIM + j0 + t2];
    vB[t2] = v[b * T_DIM + j0 + t2];
  }
  __syncthreads();

  const int wave = tid >> 6, lane = tid & 63;
  const int wr = (wave >> 1) * 64, wc = (wave & 1) * 64;
  const int l16 = lane & 15, quad = lane >> 4;

  f32x4 acc[4][4];
  #pragma unroll
  for (int mt = 0; mt < 4; ++mt)
    #pragma unroll
    for (int nt = 0; nt < 4; ++nt)
      acc[mt][nt] = (f32x4){0.f, 0.f, 0.f, 0.f};

  #pragma unroll
  for (int ks = 0; ks < 4; ++ks) {
    bf16x8 a[4], bb[4];
    const int ko = ks * 32 + quad * 8;
    #pragma unroll
    for (int mt = 0; mt < 4; ++mt)
      a[mt] = *(const bf16x8*)(As + (wr + mt * 16 + l16) * LSTRIDE + ko);
    #pragma unroll
    for (int nt = 0; nt < 4; ++nt)
      bb[nt] = *(const bf16x8*)(Bs + (wc + nt * 16 + l16) * LSTRIDE + ko);
    #pragma unroll
    for (int mt = 0; mt < 4; ++mt)
      #pragma unroll
      for (int nt = 0; nt < 4; ++nt)
        acc[mt][nt] = __builtin_amdgcn_mfma_f32_16x16x32_bf16(
            a[mt], bb[nt], acc[mt][nt], 0, 0, 0);
  }

  // Epilogue. C/D layout (m89-verified): col = lane&15, row = quad*4 + reg.
  const long baseO = (long)b * T_DIM * T_DIM;
  #pragma unroll
  for (int mt = 0; mt < 4; ++mt) {
    #pragma unroll
    for (int nt = 0; nt < 4; ++nt) {
      const f32x4 c = acc[mt][nt];
      const int col = wc + nt * 16 + l16;
      const int jg = j0 + col;
      const float hj = hB[col], vj = vB[col];
      #pragma unroll
      for (int r = 0; r < 4; ++r) {
        const int rowl = wr + mt * 16 + quad * 4 + r;
        const int ig = i0 + rowl;
        const float val = __expf(c[r] - hA[rowl] - hj) * vA[rowl] * vj;
        const float fv = val + ((ig == jg) ? JITTER_F : 0.f);
        const float yv = val + ((ig == jg) ? (JITTER_F + nA[rowl]) : 0.f);
        const long off = baseO + (long)ig * T_DIM + jg;
        __builtin_nontemporal_store(fv, f_cov + off);
        __builtin_nontemporal_store(yv, y_cov + off);
      }
    }
  }
}

extern "C" void kernel_launch(void* const* d_in, const int* in_sizes, int n_in,
                              void* d_out, int out_size, void* d_ws, size_t ws_size,
                              hipStream_t stream) {
  const float* in = (const float*)d_in[0];
  float* out = (float*)d_out;
  float* mean_out = out;                              // 16384
  float* f_cov = out + (long)B_DIM * T_DIM;           // 4*4096*4096
  float* y_cov = f_cov + (long)B_DIM * T_DIM * T_DIM; // 4*4096*4096

  char* ws = (char*)d_ws;
  bf16_t* Zb = (bf16_t*)ws;                                    // 4 MB
  float* h = (float*)(ws + (size_t)B_DIM * T_DIM * 128 * 2);   // 64 KB
  float* v = h + B_DIM * T_DIM;                                // 64 KB
  float* noise = v + B_DIM * T_DIM;                            // 64 KB

  prep_kernel<<<(B_DIM * T_DIM) / 4, 256, 0, stream>>>(in, mean_out, Zb, h, v, noise);

  dim3 grid(T_DIM / 128, T_DIM / 128, B_DIM);
  cov_kernel<<<grid, 256, 0, stream>>>(Zb, h, v, noise, f_cov, y_cov);
}

// Round 2
// 533.321 us; speedup vs baseline: 1.0806x; 1.0806x over previous
//
#include <hip/hip_runtime.h>

#define T_DIM 4096
#define B_DIM 4
#define NF 131
#define INV_SQRT_D 0.08838834764831845f
#define JITTER_F 1e-6f
#define LSTRIDE 136  // bf16 stage stride: 128+8 pad, 272 B rows, 16B-aligned
#define CSTRIDE 132  // fp32 epilogue stride: 128+4 pad, 528 B rows, 16B-aligned; 2-way banks only

typedef __bf16 bf16_t;
typedef bf16_t bf16x8 __attribute__((ext_vector_type(8)));
typedef bf16_t bf16x2 __attribute__((ext_vector_type(2)));
typedef float f32x4 __attribute__((ext_vector_type(4)));

// Kernel 1: per-row precompute.
// One wave per (b,t) row: mean copy, z -> bf16 (scaled by 1/sqrt(128)),
// h = 0.5*sum(z^2) (fp32), v, softplus(noise).
__global__ __launch_bounds__(256) void prep_kernel(
    const float* __restrict__ in, float* __restrict__ mean_out,
    bf16_t* __restrict__ Zb, float* __restrict__ h,
    float* __restrict__ v, float* __restrict__ noise) {
  const int row = blockIdx.x * 4 + (threadIdx.x >> 6);
  const int lane = threadIdx.x & 63;
  const float* x = in + (long)row * NF;
  float z0 = x[1 + lane * 2] * INV_SQRT_D;
  float z1 = x[2 + lane * 2] * INV_SQRT_D;
  bf16x2 p;
  p.x = (bf16_t)z0;
  p.y = (bf16_t)z1;
  *(bf16x2*)(Zb + (long)row * 128 + lane * 2) = p;
  float s = z0 * z0 + z1 * z1;
  #pragma unroll
  for (int m = 32; m > 0; m >>= 1) s += __shfl_down(s, m);
  if (lane == 0) {
    h[row] = 0.5f * s;
    mean_out[row] = x[0];
    v[row] = x[129];
    float t = x[130];
    noise[row] = (t > 15.0f) ? t : log1pf(__expf(t));
  }
}

// Kernel 2: 128x128 output tile per block.
// Phase 1: stage bf16 tiles, gram via mfma_f32_16x16x32_bf16.
// Phase 2: exp-epilogue into LDS (overlaying the bf16 stage buffers),
//          then row-major float4 nontemporal dual stores (full-line writes).
__global__ __launch_bounds__(256) void cov_kernel(
    const bf16_t* __restrict__ Zb, const float* __restrict__ h,
    const float* __restrict__ v, const float* __restrict__ noise,
    float* __restrict__ f_cov, float* __restrict__ y_cov) {
  __shared__ __align__(16) char smem[2 * 128 * LSTRIDE * 2];  // 69632 B
  __shared__ float hA[128], vA[128], nA[128], hB[128], vB[128];
  bf16_t* As = (bf16_t*)smem;
  bf16_t* Bs = As + 128 * LSTRIDE;

  const int jt = blockIdx.x, it = blockIdx.y, b = blockIdx.z;
  const int i0 = it * 128, j0 = jt * 128;
  const int tid = threadIdx.x;

  const bf16_t* gA = Zb + ((long)b * T_DIM + i0) * 128;
  const bf16_t* gB = Zb + ((long)b * T_DIM + j0) * 128;
  #pragma unroll
  for (int c = tid; c < 2048; c += 256) {
    const int r = c >> 4, c8 = c & 15;
    *(float4*)(As + r * LSTRIDE + c8 * 8) = ((const float4*)gA)[c];
    *(float4*)(Bs + r * LSTRIDE + c8 * 8) = ((const float4*)gB)[c];
  }
  if (tid < 128) {
    hA[tid] = h[b * T_DIM + i0 + tid];
    vA[tid] = v[b * T_DIM + i0 + tid];
    nA[tid] = noise[b * T_DIM + i0 + tid];
  } else {
    const int t2 = tid - 128;
    hB[t2] = h[b * T_DIM + j0 + t2];
    vB[t2] = v[b * T_DIM + j0 + t2];
  }
  __syncthreads();

  const int wave = tid >> 6, lane = tid & 63;
  const int wr = (wave >> 1) * 64, wc = (wave & 1) * 64;
  const int l16 = lane & 15, quad = lane >> 4;

  f32x4 acc[4][4];
  #pragma unroll
  for (int mt = 0; mt < 4; ++mt)
    #pragma unroll
    for (int nt = 0; nt < 4; ++nt)
      acc[mt][nt] = (f32x4){0.f, 0.f, 0.f, 0.f};

  #pragma unroll
  for (int ks = 0; ks < 4; ++ks) {
    bf16x8 a[4], bb[4];
    const int ko = ks * 32 + quad * 8;
    #pragma unroll
    for (int mt = 0; mt < 4; ++mt)
      a[mt] = *(const bf16x8*)(As + (wr + mt * 16 + l16) * LSTRIDE + ko);
    #pragma unroll
    for (int nt = 0; nt < 4; ++nt)
      bb[nt] = *(const bf16x8*)(Bs + (wc + nt * 16 + l16) * LSTRIDE + ko);
    #pragma unroll
    for (int mt = 0; mt < 4; ++mt)
      #pragma unroll
      for (int nt = 0; nt < 4; ++nt)
        acc[mt][nt] = __builtin_amdgcn_mfma_f32_16x16x32_bf16(
            a[mt], bb[nt], acc[mt][nt], 0, 0, 0);
  }

  __syncthreads();  // MFMA LDS reads done; safe to overlay As/Bs with fp32 tile
  float* Cs = (float*)smem;  // 128 x CSTRIDE floats = 67584 B

  // C/D layout (m89-verified): col = lane&15 (+tile offsets), row = quad*4 + reg.
  #pragma unroll
  for (int mt = 0; mt < 4; ++mt) {
    #pragma unroll
    for (int nt = 0; nt < 4; ++nt) {
      const f32x4 c = acc[mt][nt];
      const int col = wc + nt * 16 + l16;
      const float hj = hB[col], vj = vB[col];
      #pragma unroll
      for (int r = 0; r < 4; ++r) {
        const int row = wr + mt * 16 + quad * 4 + r;
        float val = __expf(c[r] - hA[row] - hj) * vA[row] * vj;
        if (it == jt && row == col) val += JITTER_F;
        Cs[row * CSTRIDE + col] = val;
      }
    }
  }
  __syncthreads();

  // Row-major readout: full-line float4 NT stores (1 KB contiguous per wave-store).
  const bool diagblk = (it == jt);
  const long baseF = (long)b * T_DIM * T_DIM + (long)i0 * T_DIM + j0;
  #pragma unroll
  for (int k = 0; k < 16; ++k) {
    const int idx = k * 256 + tid;
    const int row = idx >> 5, c4 = idx & 31;
    f32x4 val = *(const f32x4*)(Cs + row * CSTRIDE + c4 * 4);
    f32x4 yv = val;
    if (diagblk) {
      const int d = row - c4 * 4;
      if (d >= 0 && d < 4) yv[d] += nA[row];
    }
    const long off = baseF + (long)row * T_DIM + c4 * 4;
    __builtin_nontemporal_store(val, (f32x4*)(f_cov + off));
    __builtin_nontemporal_store(yv, (f32x4*)(y_cov + off));
  }
}

extern "C" void kernel_launch(void* const* d_in, const int* in_sizes, int n_in,
                              void* d_out, int out_size, void* d_ws, size_t ws_size,
                              hipStream_t stream) {
  const float* in = (const float*)d_in[0];
  float* out = (float*)d_out;
  float* mean_out = out;                              // 16384
  float* f_cov = out + (long)B_DIM * T_DIM;           // 4*4096*4096
  float* y_cov = f_cov + (long)B_DIM * T_DIM * T_DIM; // 4*4096*4096

  char* ws = (char*)d_ws;
  bf16_t* Zb = (bf16_t*)ws;                                    // 4 MB
  float* h = (float*)(ws + (size_t)B_DIM * T_DIM * 128 * 2);   // 64 KB
  float* v = h + B_DIM * T_DIM;                                // 64 KB
  float* noise = v + B_DIM * T_DIM;                            // 64 KB

  prep_kernel<<<(B_DIM * T_DIM) / 4, 256, 0, stream>>>(in, mean_out, Zb, h, v, noise);

  dim3 grid(T_DIM / 128, T_DIM / 128, B_DIM);
  cov_kernel<<<grid, 256, 0, stream>>>(Zb, h, v, noise, f_cov, y_cov);
}